// Round 5
// baseline (336.928 us; speedup 1.0000x reference)
//
#include <hip/hip_runtime.h>
#include <hip/hip_bf16.h>

#define T 2048
#define H 1024
#define IDIM 512
#define E 16
#define TOPK 4
#define NPAIR (T * TOPK)

typedef short bf16x8 __attribute__((ext_vector_type(8)));
typedef float f32x4 __attribute__((ext_vector_type(4)));

static __device__ __forceinline__ unsigned short f2bf(float f) {
    union { float f; unsigned int u; } v; v.f = f;
    unsigned int r = (v.u + 0x7FFFu + ((v.u >> 16) & 1u)) >> 16;  // RNE
    return (unsigned short)r;
}

static __device__ __forceinline__ void async_ld16(const unsigned short* g, unsigned short* l) {
    __builtin_amdgcn_global_load_lds((const __attribute__((address_space(1))) void*)g,
                                     (__attribute__((address_space(3))) void*)l, 16, 0, 0);
}

// ---------------- fp32 -> bf16 bulk convert ----------------
__global__ __launch_bounds__(256) void cvt_kernel(
    const float* __restrict__ src, unsigned short* __restrict__ dst, int n4)
{
    int i = blockIdx.x * blockDim.x + threadIdx.x;
    int stride = gridDim.x * blockDim.x;
    for (; i < n4; i += stride) {
        float4 v = ((const float4*)src)[i];
        ushort4 o;
        o.x = f2bf(v.x); o.y = f2bf(v.y); o.z = f2bf(v.z); o.w = f2bf(v.w);
        ((ushort4*)dst)[i] = o;
    }
}

// ---------------- Router (fp32, exact routing) — NO atomics ----------------
__global__ __launch_bounds__(256) void router_kernel(
    const float* __restrict__ x, const float* __restrict__ gw,
    int* __restrict__ topk_idx, float* __restrict__ topk_w)
{
    int wave = blockIdx.x * 4 + (threadIdx.x >> 6);
    int lane = threadIdx.x & 63;
    if (wave >= T) return;
    const float* xt = x + (size_t)wave * H;
    float xr[16];
#pragma unroll
    for (int j = 0; j < 16; ++j) xr[j] = xt[lane + j * 64];
    float logits[E];
#pragma unroll
    for (int e = 0; e < E; ++e) {
        const float* ge = gw + e * H;
        float acc = 0.f;
#pragma unroll
        for (int j = 0; j < 16; ++j) acc += xr[j] * ge[lane + j * 64];
#pragma unroll
        for (int off = 32; off; off >>= 1) acc += __shfl_xor(acc, off, 64);
        logits[e] = acc;
    }
    if (lane == 0) {
        float m = logits[0];
#pragma unroll
        for (int e = 1; e < E; ++e) m = fmaxf(m, logits[e]);
        float p[E];
#pragma unroll
        for (int e = 0; e < E; ++e) p[e] = __expf(logits[e] - m);
        int sel[TOPK]; float wv[TOPK]; float tot = 0.f;
#pragma unroll
        for (int k = 0; k < TOPK; ++k) {
            int best = 0; float bv = -1.f;
#pragma unroll
            for (int e = 0; e < E; ++e) { if (p[e] > bv) { bv = p[e]; best = e; } }
            sel[k] = best; wv[k] = bv; tot += bv; p[best] = -2.f;
        }
#pragma unroll
        for (int k = 0; k < TOPK; ++k) {
            topk_idx[wave * TOPK + k] = sel[k];
            topk_w[wave * TOPK + k] = wv[k] / tot;
        }
    }
}

// ---------------- Histogram + exclusive scan (one block, LDS only) ----------------
__global__ __launch_bounds__(256) void hist_kernel(
    const int* __restrict__ topk_idx, int* __restrict__ offsets)
{
    __shared__ int h[4][E];
    int tid = threadIdx.x, wave = tid >> 6;
    if (tid < 4 * E) ((int*)h)[tid] = 0;
    __syncthreads();
    for (int i = tid; i < NPAIR; i += 256) atomicAdd(&h[wave][topk_idx[i]], 1);
    __syncthreads();
    if (tid == 0) {
        int s = 0;
#pragma unroll
        for (int e = 0; e < E; ++e) {
            offsets[e] = s;
            s += h[0][e] + h[1][e] + h[2][e] + h[3][e];
        }
        offsets[E] = s;
    }
}

// ---------------- Scatter: LDS local ranks, 16 global atomics/block ----------------
__global__ __launch_bounds__(256) void scatter_kernel(
    const int* __restrict__ topk_idx,
    const int* __restrict__ offsets, int* __restrict__ cursor,
    int* __restrict__ pair_token, int* __restrict__ inv_pos)
{
    __shared__ int lh[E];
    __shared__ int base[E];
    int tid = threadIdx.x;
    int i = blockIdx.x * 256 + tid;
    if (tid < E) lh[tid] = 0;
    __syncthreads();
    int e = topk_idx[i];
    int lr = atomicAdd(&lh[e], 1);
    __syncthreads();
    if (tid < E) base[tid] = atomicAdd(&cursor[tid], lh[tid]);
    __syncthreads();
    int pos = offsets[e] + base[e] + lr;
    pair_token[pos] = i >> 2;
    inv_pos[i] = pos;
}

// ---------------- GEMM A: act = silu(Xg@w1^T) * (Xg@w3^T) ----------------
// 128x64 dual tile, BK=64, SINGLE 32KB LDS buffer, m97 2-barrier K-loop,
// 5 blocks/CU for cross-block latency hiding.
__global__ __launch_bounds__(256, 5) void gemm_a_kernel(
    const unsigned short* __restrict__ xb,
    const unsigned short* __restrict__ wb1,
    const unsigned short* __restrict__ wb3,
    const int* __restrict__ offsets,
    const int* __restrict__ pair_token,
    unsigned short* __restrict__ act)
{
    __shared__ unsigned short Xs[128 * 64];    // 16 KB
    __shared__ unsigned short W1s[64 * 64];    // 8 KB
    __shared__ unsigned short W3s[64 * 64];    // 8 KB

    int e = blockIdx.z;
    int beg = offsets[e];
    int cnt = offsets[e + 1] - beg;
    int t0 = blockIdx.x * 128;
    if (t0 >= cnt) return;
    int n0 = blockIdx.y * 64;

    int tid = threadIdx.x;
    int wave = tid >> 6, lane = tid & 63;
    int lrow8 = lane >> 3;
    int csw = (lane & 7) ^ lrow8;   // XOR swizzle on fetch side; 0 bank conflicts (R4)

    const unsigned short* xg[4];
#pragma unroll
    for (int i = 0; i < 4; ++i) {
        int row = wave * 32 + i * 8 + lrow8;
        int r = t0 + row; if (r >= cnt) r = cnt - 1;
        xg[i] = xb + (size_t)pair_token[beg + r] * H + csw * 8;
    }
    const unsigned short* w1g[2];
    const unsigned short* w3g[2];
    size_t wbase = (size_t)e * IDIM * H;
#pragma unroll
    for (int i = 0; i < 2; ++i) {
        int row = wave * 16 + i * 8 + lrow8;
        w1g[i] = wb1 + wbase + (size_t)(n0 + row) * H + csw * 8;
        w3g[i] = wb3 + wbase + (size_t)(n0 + row) * H + csw * 8;
    }

    int wr = wave >> 1, wc = wave & 1;
    int lm = lane & 15, lq = lane >> 4;

    f32x4 acc1[4][2], acc3[4][2];
#pragma unroll
    for (int mi = 0; mi < 4; ++mi)
#pragma unroll
        for (int nj = 0; nj < 2; ++nj) {
            acc1[mi][nj] = (f32x4){0.f, 0.f, 0.f, 0.f};
            acc3[mi][nj] = (f32x4){0.f, 0.f, 0.f, 0.f};
        }

    const int NK = H / 64;
    for (int kk = 0; kk < NK; ++kk) {
        int k0 = kk * 64;
        __syncthreads();   // previous compute done; LDS free
#pragma unroll
        for (int i = 0; i < 4; ++i) async_ld16(xg[i] + k0, &Xs[(wave * 32 + i * 8) * 64]);
#pragma unroll
        for (int i = 0; i < 2; ++i) {
            async_ld16(w1g[i] + k0, &W1s[(wave * 16 + i * 8) * 64]);
            async_ld16(w3g[i] + k0, &W3s[(wave * 16 + i * 8) * 64]);
        }
        __syncthreads();   // per-wave vmcnt drain -> DMA landed
#pragma unroll
        for (int ks = 0; ks < 2; ++ks) {
            int cc = ks * 4 + lq;
            bf16x8 af[4], b1[2], b3[2];
#pragma unroll
            for (int mi = 0; mi < 4; ++mi) {
                int m = wr * 64 + mi * 16 + lm;
                af[mi] = *(const bf16x8*)&Xs[m * 64 + ((cc ^ (m & 7)) << 3)];
            }
#pragma unroll
            for (int nj = 0; nj < 2; ++nj) {
                int n = wc * 32 + nj * 16 + lm;
                b1[nj] = *(const bf16x8*)&W1s[n * 64 + ((cc ^ (n & 7)) << 3)];
                b3[nj] = *(const bf16x8*)&W3s[n * 64 + ((cc ^ (n & 7)) << 3)];
            }
#pragma unroll
            for (int mi = 0; mi < 4; ++mi)
#pragma unroll
                for (int nj = 0; nj < 2; ++nj) {
                    acc1[mi][nj] = __builtin_amdgcn_mfma_f32_16x16x32_bf16(af[mi], b1[nj], acc1[mi][nj], 0, 0, 0);
                    acc3[mi][nj] = __builtin_amdgcn_mfma_f32_16x16x32_bf16(af[mi], b3[nj], acc3[mi][nj], 0, 0, 0);
                }
        }
    }
#pragma unroll
    for (int mi = 0; mi < 4; ++mi) {
#pragma unroll
        for (int r = 0; r < 4; ++r) {
            int trow = t0 + wr * 64 + mi * 16 + lq * 4 + r;
            if (trow < cnt) {
                size_t base = (size_t)(beg + trow) * IDIM + n0 + wc * 32 + lm;
#pragma unroll
                for (int nj = 0; nj < 2; ++nj) {
                    float h1 = acc1[mi][nj][r];
                    float s = h1 / (1.f + __expf(-h1));
                    act[base + nj * 16] = f2bf(s * acc3[mi][nj][r]);
                }
            }
        }
    }
}

// ---------------- GEMM B: outp[pos,:] = act @ w2^T (no atomics) ----------------
// 128x64 tile, single 24KB LDS buffer, same m97 structure.
__global__ __launch_bounds__(256, 5) void gemm_b_kernel(
    const unsigned short* __restrict__ act,
    const unsigned short* __restrict__ wb2,
    const int* __restrict__ offsets,
    float* __restrict__ outp)
{
    __shared__ unsigned short As[128 * 64];    // 16 KB
    __shared__ unsigned short W2s[64 * 64];    // 8 KB

    int e = blockIdx.z;
    int beg = offsets[e];
    int cnt = offsets[e + 1] - beg;
    int t0 = blockIdx.x * 128;
    if (t0 >= cnt) return;
    int h0 = blockIdx.y * 64;

    int tid = threadIdx.x;
    int wave = tid >> 6, lane = tid & 63;
    int lrow8 = lane >> 3;
    int csw = (lane & 7) ^ lrow8;

    const unsigned short* ag[4];
#pragma unroll
    for (int i = 0; i < 4; ++i) {
        int row = wave * 32 + i * 8 + lrow8;
        int ar = beg + t0 + row; if (ar > NPAIR - 1) ar = NPAIR - 1;
        ag[i] = act + (size_t)ar * IDIM + csw * 8;
    }
    const unsigned short* w2g[2];
    size_t wbase = (size_t)e * H * IDIM;
#pragma unroll
    for (int i = 0; i < 2; ++i) {
        int row = wave * 16 + i * 8 + lrow8;
        w2g[i] = wb2 + wbase + (size_t)(h0 + row) * IDIM + csw * 8;
    }

    int wr = wave >> 1, wc = wave & 1;
    int lm = lane & 15, lq = lane >> 4;

    f32x4 acc[4][2];
#pragma unroll
    for (int mi = 0; mi < 4; ++mi)
#pragma unroll
        for (int nj = 0; nj < 2; ++nj) acc[mi][nj] = (f32x4){0.f, 0.f, 0.f, 0.f};

    const int NK = IDIM / 64;
    for (int kk = 0; kk < NK; ++kk) {
        int k0 = kk * 64;
        __syncthreads();
#pragma unroll
        for (int i = 0; i < 4; ++i) async_ld16(ag[i] + k0, &As[(wave * 32 + i * 8) * 64]);
#pragma unroll
        for (int i = 0; i < 2; ++i) async_ld16(w2g[i] + k0, &W2s[(wave * 16 + i * 8) * 64]);
        __syncthreads();
#pragma unroll
        for (int ks = 0; ks < 2; ++ks) {
            int cc = ks * 4 + lq;
            bf16x8 af[4], bfr[2];
#pragma unroll
            for (int mi = 0; mi < 4; ++mi) {
                int m = wr * 64 + mi * 16 + lm;
                af[mi] = *(const bf16x8*)&As[m * 64 + ((cc ^ (m & 7)) << 3)];
            }
#pragma unroll
            for (int nj = 0; nj < 2; ++nj) {
                int n = wc * 32 + nj * 16 + lm;
                bfr[nj] = *(const bf16x8*)&W2s[n * 64 + ((cc ^ (n & 7)) << 3)];
            }
#pragma unroll
            for (int mi = 0; mi < 4; ++mi)
#pragma unroll
                for (int nj = 0; nj < 2; ++nj)
                    acc[mi][nj] = __builtin_amdgcn_mfma_f32_16x16x32_bf16(af[mi], bfr[nj], acc[mi][nj], 0, 0, 0);
        }
    }
#pragma unroll
    for (int mi = 0; mi < 4; ++mi) {
#pragma unroll
        for (int r = 0; r < 4; ++r) {
            int trow = t0 + wr * 64 + mi * 16 + lq * 4 + r;
            if (trow < cnt) {
                float* orow = outp + (size_t)(beg + trow) * H + h0 + wc * 32 + lm;
#pragma unroll
                for (int nj = 0; nj < 2; ++nj) orow[nj * 16] = acc[mi][nj][r];
            }
        }
    }
}

// ---------------- Combine: out[t,:] = sum_k w_k * outp[pos_k,:] ----------------
__global__ __launch_bounds__(256) void combine_kernel(
    const float* __restrict__ outp, const int* __restrict__ inv_pos,
    const float* __restrict__ topk_w, float* __restrict__ out)
{
    int gid = blockIdx.x * 256 + threadIdx.x;
    int t = gid >> 8;
    int c4 = gid & 255;
    float4 a = make_float4(0.f, 0.f, 0.f, 0.f);
#pragma unroll
    for (int k = 0; k < TOPK; ++k) {
        int pos = inv_pos[t * TOPK + k];
        float w = topk_w[t * TOPK + k];
        float4 v = *(const float4*)(outp + (size_t)pos * H + c4 * 4);
        a.x += w * v.x; a.y += w * v.y; a.z += w * v.z; a.w += w * v.w;
    }
    *(float4*)(out + (size_t)t * H + c4 * 4) = a;
}

extern "C" void kernel_launch(void* const* d_in, const int* in_sizes, int n_in,
                              void* d_out, int out_size, void* d_ws, size_t ws_size,
                              hipStream_t stream)
{
    const float* x  = (const float*)d_in[0];
    const float* gw = (const float*)d_in[1];
    const float* w1 = (const float*)d_in[2];
    const float* w3 = (const float*)d_in[3];
    const float* w2 = (const float*)d_in[4];
    float* out = (float*)d_out;

    char* ws = (char*)d_ws;
    int*   cursor     = (int*)(ws + 64);
    int*   offsets    = (int*)(ws + 128);
    int*   topk_idx   = (int*)(ws + 1024);
    float* topk_w     = (float*)(ws + 33792);
    int*   pair_token = (int*)(ws + 66560);
    int*   inv_pos    = (int*)(ws + 99328);
    unsigned short* xb  = (unsigned short*)(ws + 262144);    // 4 MB
    unsigned short* wb1 = (unsigned short*)(ws + 8388608);   // 16 MB
    unsigned short* wb3 = (unsigned short*)(ws + 25165824);  // 16 MB
    unsigned short* wb2 = (unsigned short*)(ws + 41943040);  // 16 MB
    unsigned short* act = (unsigned short*)(ws + 58720256);  // 8 MB
    float* outp = (float*)(ws + 8388608);  // aliases wb1+wb3 (dead after gemm_a), 32 MB

    hipMemsetAsync(ws, 0, 256, stream);

    router_kernel<<<T / 4, 256, 0, stream>>>(x, gw, topk_idx, topk_w);
    hist_kernel<<<1, 256, 0, stream>>>(topk_idx, offsets);
    scatter_kernel<<<NPAIR / 256, 256, 0, stream>>>(topk_idx, offsets, cursor,
                                                    pair_token, inv_pos);

    cvt_kernel<<<512, 256, 0, stream>>>(x, xb, (T * H) / 4);
    cvt_kernel<<<2048, 256, 0, stream>>>(w1, wb1, (E * IDIM * H) / 4);
    cvt_kernel<<<2048, 256, 0, stream>>>(w3, wb3, (E * IDIM * H) / 4);
    cvt_kernel<<<2048, 256, 0, stream>>>(w2, wb2, (E * H * IDIM) / 4);

    gemm_a_kernel<<<dim3(16, IDIM / 64, E), 256, 0, stream>>>(xb, wb1, wb3, offsets,
                                                              pair_token, act);
    gemm_b_kernel<<<dim3(16, H / 64, E), 256, 0, stream>>>(act, wb2, offsets, outp);
    combine_kernel<<<(T * H / 4) / 256, 256, 0, stream>>>(outp, inv_pos, topk_w, out);
}

// Round 6
// 234.441 us; speedup vs baseline: 1.4372x; 1.4372x over previous
//
#include <hip/hip_runtime.h>
#include <hip/hip_bf16.h>

#define T 2048
#define H 1024
#define IDIM 512
#define E 16
#define TOPK 4
#define NPAIR (T * TOPK)

typedef short bf16x8 __attribute__((ext_vector_type(8)));
typedef float f32x4 __attribute__((ext_vector_type(4)));

static __device__ __forceinline__ unsigned short f2bf(float f) {
    union { float f; unsigned int u; } v; v.f = f;
    unsigned int r = (v.u + 0x7FFFu + ((v.u >> 16) & 1u)) >> 16;  // RNE
    return (unsigned short)r;
}
static __device__ __forceinline__ float bf2f(unsigned short s) {
    union { unsigned int u; float f; } v; v.u = ((unsigned int)s) << 16;
    return v.f;
}

static __device__ __forceinline__ void async_ld16(const unsigned short* g, unsigned short* l) {
    __builtin_amdgcn_global_load_lds((const __attribute__((address_space(1))) void*)g,
                                     (__attribute__((address_space(3))) void*)l, 16, 0, 0);
}

// ---------------- fp32 -> bf16 bulk convert (weights) ----------------
__global__ __launch_bounds__(256) void cvt_kernel(
    const float* __restrict__ src, unsigned short* __restrict__ dst, int n4)
{
    int i = blockIdx.x * blockDim.x + threadIdx.x;
    int stride = gridDim.x * blockDim.x;
    for (; i < n4; i += stride) {
        float4 v = ((const float4*)src)[i];
        ushort4 o;
        o.x = f2bf(v.x); o.y = f2bf(v.y); o.z = f2bf(v.z); o.w = f2bf(v.w);
        ((ushort4*)dst)[i] = o;
    }
}

// ---------------- Router (fp32 exact) + fused x->bf16 ----------------
__global__ __launch_bounds__(256) void router_kernel(
    const float* __restrict__ x, const float* __restrict__ gw,
    int* __restrict__ topk_idx, float* __restrict__ topk_w,
    unsigned short* __restrict__ xb)
{
    int tok = blockIdx.x * 4 + (threadIdx.x >> 6);
    int lane = threadIdx.x & 63;
    if (tok >= T) return;
    const float4* xt4 = (const float4*)(x + (size_t)tok * H);
    float4 xr[4];
#pragma unroll
    for (int j = 0; j < 4; ++j) xr[j] = xt4[lane + j * 64];
    // fused x -> bf16 (replaces x cvt kernel)
    ushort4* xbt = (ushort4*)(xb + (size_t)tok * H);
#pragma unroll
    for (int j = 0; j < 4; ++j) {
        ushort4 o;
        o.x = f2bf(xr[j].x); o.y = f2bf(xr[j].y);
        o.z = f2bf(xr[j].z); o.w = f2bf(xr[j].w);
        xbt[lane + j * 64] = o;
    }
    float logits[E];
#pragma unroll
    for (int e = 0; e < E; ++e) {
        const float4* ge4 = (const float4*)(gw + (size_t)e * H);
        float acc = 0.f;
#pragma unroll
        for (int j = 0; j < 4; ++j) {
            float4 g = ge4[lane + j * 64];
            acc += xr[j].x * g.x + xr[j].y * g.y + xr[j].z * g.z + xr[j].w * g.w;
        }
#pragma unroll
        for (int off = 32; off; off >>= 1) acc += __shfl_xor(acc, off, 64);
        logits[e] = acc;
    }
    if (lane == 0) {
        float m = logits[0];
#pragma unroll
        for (int e = 1; e < E; ++e) m = fmaxf(m, logits[e]);
        float p[E];
#pragma unroll
        for (int e = 0; e < E; ++e) p[e] = __expf(logits[e] - m);
        int sel[TOPK]; float wv[TOPK]; float tot = 0.f;
#pragma unroll
        for (int k = 0; k < TOPK; ++k) {
            int best = 0; float bv = -1.f;
#pragma unroll
            for (int e = 0; e < E; ++e) { if (p[e] > bv) { bv = p[e]; best = e; } }
            sel[k] = best; wv[k] = bv; tot += bv; p[best] = -2.f;
        }
#pragma unroll
        for (int k = 0; k < TOPK; ++k) {
            topk_idx[tok * TOPK + k] = sel[k];
            topk_w[tok * TOPK + k] = wv[k] / tot;
        }
    }
}

// ---------------- Histogram + scan (one block) ----------------
__global__ __launch_bounds__(256) void hist_kernel(
    const int* __restrict__ topk_idx, int* __restrict__ offsets)
{
    __shared__ int h[4][E];
    int tid = threadIdx.x, wave = tid >> 6;
    if (tid < 4 * E) ((int*)h)[tid] = 0;
    __syncthreads();
    for (int i = tid; i < NPAIR; i += 256) atomicAdd(&h[wave][topk_idx[i]], 1);
    __syncthreads();
    if (tid == 0) {
        int s = 0;
#pragma unroll
        for (int e = 0; e < E; ++e) {
            offsets[e] = s;
            s += h[0][e] + h[1][e] + h[2][e] + h[3][e];
        }
        offsets[E] = s;
    }
}

// ---------------- Scatter ----------------
__global__ __launch_bounds__(256) void scatter_kernel(
    const int* __restrict__ topk_idx,
    const int* __restrict__ offsets, int* __restrict__ cursor,
    int* __restrict__ pair_token, int* __restrict__ inv_pos)
{
    __shared__ int lh[E];
    __shared__ int base[E];
    int tid = threadIdx.x;
    int i = blockIdx.x * 256 + tid;
    if (tid < E) lh[tid] = 0;
    __syncthreads();
    int e = topk_idx[i];
    int lr = atomicAdd(&lh[e], 1);
    __syncthreads();
    if (tid < E) base[tid] = atomicAdd(&cursor[tid], lh[tid]);
    __syncthreads();
    int pos = offsets[e] + base[e] + lr;
    pair_token[pos] = i >> 2;
    inv_pos[i] = pos;
}

// ---------------- GEMM A: act = silu(Xg@w1^T)*(Xg@w3^T) ----------------
// R4 dbuf structure + XCD-aware 1-D swizzle: all token-tile siblings sharing a
// weight tile (n0,e) land on the SAME XCD (bid&7) for L2 weight reuse.
__global__ __launch_bounds__(256) void gemm_a_kernel(
    const unsigned short* __restrict__ xb,
    const unsigned short* __restrict__ wb1,
    const unsigned short* __restrict__ wb3,
    const int* __restrict__ offsets,
    const int* __restrict__ pair_token,
    unsigned short* __restrict__ act)
{
    __shared__ unsigned short Xs[2][128 * 64];
    __shared__ unsigned short W1s[2][64 * 64];
    __shared__ unsigned short W3s[2][64 * 64];

    // grid = 2048 1-D: xcd=bid&7; s=bid>>3; yz=xcd*16+(s>>4); x=s&15
    int bid = blockIdx.x;
    int xcd = bid & 7, s = bid >> 3;
    int yz = xcd * 16 + (s >> 4);   // 128 (n-tile,expert) pairs, 16 per XCD
    int e = yz >> 3;
    int n0 = (yz & 7) * 64;
    int t0 = (s & 15) * 128;

    int beg = offsets[e];
    int cnt = offsets[e + 1] - beg;
    if (t0 >= cnt) return;

    int tid = threadIdx.x;
    int wave = tid >> 6, lane = tid & 63;
    int lrow8 = lane >> 3;
    int csw = (lane & 7) ^ lrow8;   // XOR swizzle; 0 bank conflicts (verified R4)

    const unsigned short* xg[4];
#pragma unroll
    for (int i = 0; i < 4; ++i) {
        int row = wave * 32 + i * 8 + lrow8;
        int r = t0 + row; if (r >= cnt) r = cnt - 1;
        xg[i] = xb + (size_t)pair_token[beg + r] * H + csw * 8;
    }
    const unsigned short* w1g[2];
    const unsigned short* w3g[2];
    size_t wbase = (size_t)e * IDIM * H;
#pragma unroll
    for (int i = 0; i < 2; ++i) {
        int row = wave * 16 + i * 8 + lrow8;
        w1g[i] = wb1 + wbase + (size_t)(n0 + row) * H + csw * 8;
        w3g[i] = wb3 + wbase + (size_t)(n0 + row) * H + csw * 8;
    }

    int wr = wave >> 1, wc = wave & 1;
    int lm = lane & 15, lq = lane >> 4;

    f32x4 acc1[4][2], acc3[4][2];
#pragma unroll
    for (int mi = 0; mi < 4; ++mi)
#pragma unroll
        for (int nj = 0; nj < 2; ++nj) {
            acc1[mi][nj] = (f32x4){0.f, 0.f, 0.f, 0.f};
            acc3[mi][nj] = (f32x4){0.f, 0.f, 0.f, 0.f};
        }

#pragma unroll
    for (int i = 0; i < 4; ++i) async_ld16(xg[i], &Xs[0][(wave * 32 + i * 8) * 64]);
#pragma unroll
    for (int i = 0; i < 2; ++i) {
        async_ld16(w1g[i], &W1s[0][(wave * 16 + i * 8) * 64]);
        async_ld16(w3g[i], &W3s[0][(wave * 16 + i * 8) * 64]);
    }

    const int NK = H / 64;
    for (int kk = 0; kk < NK; ++kk) {
        int cur = kk & 1;
        __syncthreads();
        if (kk + 1 < NK) {
            int nxt = cur ^ 1;
            int k1 = (kk + 1) * 64;
#pragma unroll
            for (int i = 0; i < 4; ++i) async_ld16(xg[i] + k1, &Xs[nxt][(wave * 32 + i * 8) * 64]);
#pragma unroll
            for (int i = 0; i < 2; ++i) {
                async_ld16(w1g[i] + k1, &W1s[nxt][(wave * 16 + i * 8) * 64]);
                async_ld16(w3g[i] + k1, &W3s[nxt][(wave * 16 + i * 8) * 64]);
            }
        }
#pragma unroll
        for (int ks = 0; ks < 2; ++ks) {
            int cc = ks * 4 + lq;
            bf16x8 af[4], b1[2], b3[2];
#pragma unroll
            for (int mi = 0; mi < 4; ++mi) {
                int m = wr * 64 + mi * 16 + lm;
                af[mi] = *(const bf16x8*)&Xs[cur][m * 64 + ((cc ^ (m & 7)) << 3)];
            }
#pragma unroll
            for (int nj = 0; nj < 2; ++nj) {
                int n = wc * 32 + nj * 16 + lm;
                b1[nj] = *(const bf16x8*)&W1s[cur][n * 64 + ((cc ^ (n & 7)) << 3)];
                b3[nj] = *(const bf16x8*)&W3s[cur][n * 64 + ((cc ^ (n & 7)) << 3)];
            }
#pragma unroll
            for (int mi = 0; mi < 4; ++mi)
#pragma unroll
                for (int nj = 0; nj < 2; ++nj) {
                    acc1[mi][nj] = __builtin_amdgcn_mfma_f32_16x16x32_bf16(af[mi], b1[nj], acc1[mi][nj], 0, 0, 0);
                    acc3[mi][nj] = __builtin_amdgcn_mfma_f32_16x16x32_bf16(af[mi], b3[nj], acc3[mi][nj], 0, 0, 0);
                }
        }
    }
#pragma unroll
    for (int mi = 0; mi < 4; ++mi) {
#pragma unroll
        for (int r = 0; r < 4; ++r) {
            int trow = t0 + wr * 64 + mi * 16 + lq * 4 + r;
            if (trow < cnt) {
                size_t base = (size_t)(beg + trow) * IDIM + n0 + wc * 32 + lm;
#pragma unroll
                for (int nj = 0; nj < 2; ++nj) {
                    float h1 = acc1[mi][nj][r];
                    float sg = h1 / (1.f + __expf(-h1));
                    act[base + nj * 16] = f2bf(sg * acc3[mi][nj][r]);
                }
            }
        }
    }
}

// ---------------- GEMM B: outp_bf16[pos,:] = act @ w2^T ----------------
__global__ __launch_bounds__(256) void gemm_b_kernel(
    const unsigned short* __restrict__ act,
    const unsigned short* __restrict__ wb2,
    const int* __restrict__ offsets,
    unsigned short* __restrict__ outp)
{
    __shared__ unsigned short As[2][128 * 64];
    __shared__ unsigned short W2s[2][64 * 64];

    // grid = 4096 1-D: xcd=bid&7; s=bid>>3 (512/xcd); yz=xcd*32+(s>>4); x=s&15
    int bid = blockIdx.x;
    int xcd = bid & 7, s = bid >> 3;
    int yz = xcd * 32 + (s >> 4);   // 256 (h-tile,expert) pairs, 32 per XCD
    int e = yz >> 4;
    int h0 = (yz & 15) * 64;
    int t0 = (s & 15) * 128;

    int beg = offsets[e];
    int cnt = offsets[e + 1] - beg;
    if (t0 >= cnt) return;

    int tid = threadIdx.x;
    int wave = tid >> 6, lane = tid & 63;
    int lrow8 = lane >> 3;
    int csw = (lane & 7) ^ lrow8;

    const unsigned short* ag[4];
#pragma unroll
    for (int i = 0; i < 4; ++i) {
        int row = wave * 32 + i * 8 + lrow8;
        int ar = beg + t0 + row; if (ar > NPAIR - 1) ar = NPAIR - 1;
        ag[i] = act + (size_t)ar * IDIM + csw * 8;
    }
    const unsigned short* w2g[2];
    size_t wbase = (size_t)e * H * IDIM;
#pragma unroll
    for (int i = 0; i < 2; ++i) {
        int row = wave * 16 + i * 8 + lrow8;
        w2g[i] = wb2 + wbase + (size_t)(h0 + row) * IDIM + csw * 8;
    }

    int wr = wave >> 1, wc = wave & 1;
    int lm = lane & 15, lq = lane >> 4;

    f32x4 acc[4][2];
#pragma unroll
    for (int mi = 0; mi < 4; ++mi)
#pragma unroll
        for (int nj = 0; nj < 2; ++nj) acc[mi][nj] = (f32x4){0.f, 0.f, 0.f, 0.f};

#pragma unroll
    for (int i = 0; i < 4; ++i) async_ld16(ag[i], &As[0][(wave * 32 + i * 8) * 64]);
#pragma unroll
    for (int i = 0; i < 2; ++i) async_ld16(w2g[i], &W2s[0][(wave * 16 + i * 8) * 64]);

    const int NK = IDIM / 64;
    for (int kk = 0; kk < NK; ++kk) {
        int cur = kk & 1;
        __syncthreads();
        if (kk + 1 < NK) {
            int nxt = cur ^ 1;
            int k1 = (kk + 1) * 64;
#pragma unroll
            for (int i = 0; i < 4; ++i) async_ld16(ag[i] + k1, &As[nxt][(wave * 32 + i * 8) * 64]);
#pragma unroll
            for (int i = 0; i < 2; ++i) async_ld16(w2g[i] + k1, &W2s[nxt][(wave * 16 + i * 8) * 64]);
        }
#pragma unroll
        for (int ks = 0; ks < 2; ++ks) {
            int cc = ks * 4 + lq;
            bf16x8 af[4], bfr[2];
#pragma unroll
            for (int mi = 0; mi < 4; ++mi) {
                int m = wr * 64 + mi * 16 + lm;
                af[mi] = *(const bf16x8*)&As[cur][m * 64 + ((cc ^ (m & 7)) << 3)];
            }
#pragma unroll
            for (int nj = 0; nj < 2; ++nj) {
                int n = wc * 32 + nj * 16 + lm;
                bfr[nj] = *(const bf16x8*)&W2s[cur][n * 64 + ((cc ^ (n & 7)) << 3)];
            }
#pragma unroll
            for (int mi = 0; mi < 4; ++mi)
#pragma unroll
                for (int nj = 0; nj < 2; ++nj)
                    acc[mi][nj] = __builtin_amdgcn_mfma_f32_16x16x32_bf16(af[mi], bfr[nj], acc[mi][nj], 0, 0, 0);
        }
    }
#pragma unroll
    for (int mi = 0; mi < 4; ++mi) {
#pragma unroll
        for (int r = 0; r < 4; ++r) {
            int trow = t0 + wr * 64 + mi * 16 + lq * 4 + r;
            if (trow < cnt) {
                unsigned short* orow = outp + (size_t)(beg + trow) * H + h0 + wc * 32 + lm;
#pragma unroll
                for (int nj = 0; nj < 2; ++nj) orow[nj * 16] = f2bf(acc[mi][nj][r]);
            }
        }
    }
}

// ---------------- Combine: out[t,:] = sum_k w_k * outp[pos_k,:] ----------------
__global__ __launch_bounds__(256) void combine_kernel(
    const unsigned short* __restrict__ outp, const int* __restrict__ inv_pos,
    const float* __restrict__ topk_w, float* __restrict__ out)
{
    int gid = blockIdx.x * 256 + threadIdx.x;
    int t = gid >> 8;
    int c4 = gid & 255;
    float4 a = make_float4(0.f, 0.f, 0.f, 0.f);
#pragma unroll
    for (int k = 0; k < TOPK; ++k) {
        int pos = inv_pos[t * TOPK + k];
        float w = topk_w[t * TOPK + k];
        ushort4 v = ((const ushort4*)(outp + (size_t)pos * H))[c4];
        a.x += w * bf2f(v.x); a.y += w * bf2f(v.y);
        a.z += w * bf2f(v.z); a.w += w * bf2f(v.w);
    }
    *(float4*)(out + (size_t)t * H + c4 * 4) = a;
}

extern "C" void kernel_launch(void* const* d_in, const int* in_sizes, int n_in,
                              void* d_out, int out_size, void* d_ws, size_t ws_size,
                              hipStream_t stream)
{
    const float* x  = (const float*)d_in[0];
    const float* gw = (const float*)d_in[1];
    const float* w1 = (const float*)d_in[2];
    const float* w3 = (const float*)d_in[3];
    const float* w2 = (const float*)d_in[4];
    float* out = (float*)d_out;

    char* ws = (char*)d_ws;
    int*   cursor     = (int*)(ws + 64);
    int*   offsets    = (int*)(ws + 128);
    int*   topk_idx   = (int*)(ws + 1024);
    float* topk_w     = (float*)(ws + 33792);
    int*   pair_token = (int*)(ws + 66560);
    int*   inv_pos    = (int*)(ws + 99328);
    unsigned short* xb  = (unsigned short*)(ws + 262144);    // 4 MB
    unsigned short* wb1 = (unsigned short*)(ws + 8388608);   // 16 MB
    unsigned short* wb3 = (unsigned short*)(ws + 25165824);  // 16 MB
    unsigned short* wb2 = (unsigned short*)(ws + 41943040);  // 16 MB
    unsigned short* act = (unsigned short*)(ws + 58720256);  // 8 MB
    unsigned short* outp = (unsigned short*)(ws + 8388608);  // bf16 16 MB, aliases wb1

    hipMemsetAsync(ws, 0, 256, stream);

    router_kernel<<<T / 4, 256, 0, stream>>>(x, gw, topk_idx, topk_w, xb);
    hist_kernel<<<1, 256, 0, stream>>>(topk_idx, offsets);
    scatter_kernel<<<NPAIR / 256, 256, 0, stream>>>(topk_idx, offsets, cursor,
                                                    pair_token, inv_pos);

    cvt_kernel<<<2048, 256, 0, stream>>>(w1, wb1, (E * IDIM * H) / 4);
    cvt_kernel<<<2048, 256, 0, stream>>>(w3, wb3, (E * IDIM * H) / 4);
    cvt_kernel<<<2048, 256, 0, stream>>>(w2, wb2, (E * H * IDIM) / 4);

    gemm_a_kernel<<<2048, 256, 0, stream>>>(xb, wb1, wb3, offsets, pair_token, act);
    gemm_b_kernel<<<4096, 256, 0, stream>>>(act, wb2, offsets, outp);
    combine_kernel<<<(T * H / 4) / 256, 256, 0, stream>>>(outp, inv_pos, topk_w, out);
}

// Round 7
// 229.276 us; speedup vs baseline: 1.4695x; 1.0225x over previous
//
#include <hip/hip_runtime.h>
#include <hip/hip_bf16.h>

#define T 2048
#define H 1024
#define IDIM 512
#define E 16
#define TOPK 4
#define NPAIR (T * TOPK)

typedef short bf16x8 __attribute__((ext_vector_type(8)));
typedef float f32x4 __attribute__((ext_vector_type(4)));

static __device__ __forceinline__ unsigned short f2bf(float f) {
    union { float f; unsigned int u; } v; v.f = f;
    unsigned int r = (v.u + 0x7FFFu + ((v.u >> 16) & 1u)) >> 16;  // RNE
    return (unsigned short)r;
}
static __device__ __forceinline__ float bf2f(unsigned short s) {
    union { unsigned int u; float f; } v; v.u = ((unsigned int)s) << 16;
    return v.f;
}

static __device__ __forceinline__ void async_ld16(const unsigned short* g, unsigned short* l) {
    __builtin_amdgcn_global_load_lds((const __attribute__((address_space(1))) void*)g,
                                     (__attribute__((address_space(3))) void*)l, 16, 0, 0);
}

// ---------------- fp32 -> bf16: all three weights in ONE launch ----------------
__global__ __launch_bounds__(256) void cvt3_kernel(
    const float* __restrict__ w1, const float* __restrict__ w3, const float* __restrict__ w2,
    unsigned short* __restrict__ d1, unsigned short* __restrict__ d3, unsigned short* __restrict__ d2)
{
    const int n4 = (E * IDIM * H) / 4;      // per-region float4 count
    int region = blockIdx.x >> 11;          // 3 regions x 2048 blocks
    int bid = blockIdx.x & 2047;
    const float* src = (region == 0) ? w1 : (region == 1) ? w3 : w2;
    unsigned short* dst = (region == 0) ? d1 : (region == 1) ? d3 : d2;
    int i = bid * 256 + threadIdx.x;
    const int stride = 2048 * 256;
#pragma unroll 4
    for (; i < n4; i += stride) {
        float4 v = ((const float4*)src)[i];
        ushort4 o;
        o.x = f2bf(v.x); o.y = f2bf(v.y); o.z = f2bf(v.z); o.w = f2bf(v.w);
        ((ushort4*)dst)[i] = o;
    }
}

// ---------------- Router (fp32 exact) + fused x->bf16 ----------------
__global__ __launch_bounds__(256) void router_kernel(
    const float* __restrict__ x, const float* __restrict__ gw,
    int* __restrict__ topk_idx, float* __restrict__ topk_w,
    unsigned short* __restrict__ xb)
{
    int tok = blockIdx.x * 4 + (threadIdx.x >> 6);
    int lane = threadIdx.x & 63;
    if (tok >= T) return;
    const float4* xt4 = (const float4*)(x + (size_t)tok * H);
    float4 xr[4];
#pragma unroll
    for (int j = 0; j < 4; ++j) xr[j] = xt4[lane + j * 64];
    ushort4* xbt = (ushort4*)(xb + (size_t)tok * H);
#pragma unroll
    for (int j = 0; j < 4; ++j) {
        ushort4 o;
        o.x = f2bf(xr[j].x); o.y = f2bf(xr[j].y);
        o.z = f2bf(xr[j].z); o.w = f2bf(xr[j].w);
        xbt[lane + j * 64] = o;
    }
    float logits[E];
#pragma unroll
    for (int e = 0; e < E; ++e) {
        const float4* ge4 = (const float4*)(gw + (size_t)e * H);
        float acc = 0.f;
#pragma unroll
        for (int j = 0; j < 4; ++j) {
            float4 g = ge4[lane + j * 64];
            acc += xr[j].x * g.x + xr[j].y * g.y + xr[j].z * g.z + xr[j].w * g.w;
        }
#pragma unroll
        for (int off = 32; off; off >>= 1) acc += __shfl_xor(acc, off, 64);
        logits[e] = acc;
    }
    if (lane == 0) {
        float m = logits[0];
#pragma unroll
        for (int e = 1; e < E; ++e) m = fmaxf(m, logits[e]);
        float p[E];
#pragma unroll
        for (int e = 0; e < E; ++e) p[e] = __expf(logits[e] - m);
        int sel[TOPK]; float wv[TOPK]; float tot = 0.f;
#pragma unroll
        for (int k = 0; k < TOPK; ++k) {
            int best = 0; float bv = -1.f;
#pragma unroll
            for (int e = 0; e < E; ++e) { if (p[e] > bv) { bv = p[e]; best = e; } }
            sel[k] = best; wv[k] = bv; tot += bv; p[best] = -2.f;
        }
#pragma unroll
        for (int k = 0; k < TOPK; ++k) {
            topk_idx[tok * TOPK + k] = sel[k];
            topk_w[tok * TOPK + k] = wv[k] / tot;
        }
    }
}

// ---------------- Histogram + scan ----------------
__global__ __launch_bounds__(256) void hist_kernel(
    const int* __restrict__ topk_idx, int* __restrict__ offsets)
{
    __shared__ int h[4][E];
    int tid = threadIdx.x, wave = tid >> 6;
    if (tid < 4 * E) ((int*)h)[tid] = 0;
    __syncthreads();
    for (int i = tid; i < NPAIR; i += 256) atomicAdd(&h[wave][topk_idx[i]], 1);
    __syncthreads();
    if (tid == 0) {
        int s = 0;
#pragma unroll
        for (int e = 0; e < E; ++e) {
            offsets[e] = s;
            s += h[0][e] + h[1][e] + h[2][e] + h[3][e];
        }
        offsets[E] = s;
    }
}

// ---------------- Scatter ----------------
__global__ __launch_bounds__(256) void scatter_kernel(
    const int* __restrict__ topk_idx,
    const int* __restrict__ offsets, int* __restrict__ cursor,
    int* __restrict__ pair_token, int* __restrict__ inv_pos)
{
    __shared__ int lh[E];
    __shared__ int base[E];
    int tid = threadIdx.x;
    int i = blockIdx.x * 256 + tid;
    if (tid < E) lh[tid] = 0;
    __syncthreads();
    int e = topk_idx[i];
    int lr = atomicAdd(&lh[e], 1);
    __syncthreads();
    if (tid < E) base[tid] = atomicAdd(&cursor[tid], lh[tid]);
    __syncthreads();
    int pos = offsets[e] + base[e] + lr;
    pair_token[pos] = i >> 2;
    inv_pos[i] = pos;
}

// Swizzle (BK=32): global (row, chunk c in 0..3) stored at 16B-slot
//   s = (c + 4*(row&1)) ^ ((row>>1)&7) within 2-row granule (row>>1).
// Read (m, cc): addr_elems = (m>>1)*64 + ((cc + 4*(m&1)) ^ ((m>>1)&7))*8.
// Balance proof: per ds_read_b128 each bank-quad gets exactly 8 of 64 lanes.

// ---------------- GEMM A: act = silu(Xg@w1^T)*(Xg@w3^T) ----------------
// 128x64 dual tile, BK=32, dbuf 32KB LDS -> 5 blocks/CU, XCD swizzle.
__global__ __launch_bounds__(256, 5) void gemm_a_kernel(
    const unsigned short* __restrict__ xb,
    const unsigned short* __restrict__ wb1,
    const unsigned short* __restrict__ wb3,
    const int* __restrict__ offsets,
    const int* __restrict__ pair_token,
    unsigned short* __restrict__ act)
{
    __shared__ unsigned short Xs[2][128 * 32];   // 2 x 8 KB
    __shared__ unsigned short W1s[2][64 * 32];   // 2 x 4 KB
    __shared__ unsigned short W3s[2][64 * 32];   // 2 x 4 KB

    int bid = blockIdx.x;
    int xcd = bid & 7, s0 = bid >> 3;
    int yz = xcd * 16 + (s0 >> 4);
    int e = yz >> 3;
    int n0 = (yz & 7) * 64;
    int t0 = (s0 & 15) * 128;

    int beg = offsets[e];
    int cnt = offsets[e + 1] - beg;
    if (t0 >= cnt) return;

    int tid = threadIdx.x;
    int wave = tid >> 6, lane = tid & 63;

    // staging source pointers (k-invariant): slot -> (row, chunk) via swizzle
    const unsigned short* xg[2];
#pragma unroll
    for (int i = 0; i < 2; ++i) {
        int slot = wave * 128 + i * 64 + lane;
        int g = slot >> 3, sp = (slot & 7) ^ (g & 7);
        int row = g * 2 + (sp >> 2), c = sp & 3;
        int r = t0 + row; if (r >= cnt) r = cnt - 1;
        xg[i] = xb + (size_t)pair_token[beg + r] * H + c * 8;
    }
    const unsigned short* w1g;
    const unsigned short* w3g;
    {
        int slot = wave * 64 + lane;
        int g = slot >> 3, sp = (slot & 7) ^ (g & 7);
        int row = g * 2 + (sp >> 2), c = sp & 3;
        size_t off = (size_t)e * IDIM * H + (size_t)(n0 + row) * H + c * 8;
        w1g = wb1 + off;
        w3g = wb3 + off;
    }

    int wr = wave >> 1, wc = wave & 1;
    int lm = lane & 15, lq = lane >> 4;

    f32x4 acc1[4][2], acc3[4][2];
#pragma unroll
    for (int mi = 0; mi < 4; ++mi)
#pragma unroll
        for (int nj = 0; nj < 2; ++nj) {
            acc1[mi][nj] = (f32x4){0.f, 0.f, 0.f, 0.f};
            acc3[mi][nj] = (f32x4){0.f, 0.f, 0.f, 0.f};
        }

    // precompute frag-read LDS offsets (element units)
    int aoff[4], boff[2];
#pragma unroll
    for (int mi = 0; mi < 4; ++mi) {
        int m = wr * 64 + mi * 16 + lm;
        int g = m >> 1;
        aoff[mi] = g * 64 + (((lq + ((m & 1) << 2)) ^ (g & 7)) << 3);
    }
#pragma unroll
    for (int nj = 0; nj < 2; ++nj) {
        int n = wc * 32 + nj * 16 + lm;
        int g = n >> 1;
        boff[nj] = g * 64 + (((lq + ((n & 1) << 2)) ^ (g & 7)) << 3);
    }

    // prologue
#pragma unroll
    for (int i = 0; i < 2; ++i) async_ld16(xg[i], &Xs[0][(wave * 128 + i * 64) * 8]);
    async_ld16(w1g, &W1s[0][wave * 512]);
    async_ld16(w3g, &W3s[0][wave * 512]);

    const int NK = H / 32;
    for (int kk = 0; kk < NK; ++kk) {
        int cur = kk & 1;
        __syncthreads();
        if (kk + 1 < NK) {
            int nxt = cur ^ 1;
            int k1 = (kk + 1) * 32;
#pragma unroll
            for (int i = 0; i < 2; ++i) async_ld16(xg[i] + k1, &Xs[nxt][(wave * 128 + i * 64) * 8]);
            async_ld16(w1g + k1, &W1s[nxt][wave * 512]);
            async_ld16(w3g + k1, &W3s[nxt][wave * 512]);
        }
        bf16x8 af[4], b1[2], b3[2];
#pragma unroll
        for (int mi = 0; mi < 4; ++mi) af[mi] = *(const bf16x8*)&Xs[cur][aoff[mi]];
#pragma unroll
        for (int nj = 0; nj < 2; ++nj) {
            b1[nj] = *(const bf16x8*)&W1s[cur][boff[nj]];
            b3[nj] = *(const bf16x8*)&W3s[cur][boff[nj]];
        }
#pragma unroll
        for (int mi = 0; mi < 4; ++mi)
#pragma unroll
            for (int nj = 0; nj < 2; ++nj) {
                acc1[mi][nj] = __builtin_amdgcn_mfma_f32_16x16x32_bf16(af[mi], b1[nj], acc1[mi][nj], 0, 0, 0);
                acc3[mi][nj] = __builtin_amdgcn_mfma_f32_16x16x32_bf16(af[mi], b3[nj], acc3[mi][nj], 0, 0, 0);
            }
    }
#pragma unroll
    for (int mi = 0; mi < 4; ++mi) {
#pragma unroll
        for (int r = 0; r < 4; ++r) {
            int trow = t0 + wr * 64 + mi * 16 + lq * 4 + r;
            if (trow < cnt) {
                size_t base = (size_t)(beg + trow) * IDIM + n0 + wc * 32 + lm;
#pragma unroll
                for (int nj = 0; nj < 2; ++nj) {
                    float h1 = acc1[mi][nj][r];
                    float sg = h1 / (1.f + __expf(-h1));
                    act[base + nj * 16] = f2bf(sg * acc3[mi][nj][r]);
                }
            }
        }
    }
}

// ---------------- GEMM B: outp_bf16[pos,:] = act @ w2^T ----------------
// 128x64 tile, BK=32, dbuf 24KB LDS, XCD swizzle.
__global__ __launch_bounds__(256, 5) void gemm_b_kernel(
    const unsigned short* __restrict__ act,
    const unsigned short* __restrict__ wb2,
    const int* __restrict__ offsets,
    unsigned short* __restrict__ outp)
{
    __shared__ unsigned short As[2][128 * 32];
    __shared__ unsigned short W2s[2][64 * 32];

    int bid = blockIdx.x;
    int xcd = bid & 7, s0 = bid >> 3;
    int yz = xcd * 32 + (s0 >> 4);
    int e = yz >> 4;
    int h0 = (yz & 15) * 64;
    int t0 = (s0 & 15) * 128;

    int beg = offsets[e];
    int cnt = offsets[e + 1] - beg;
    if (t0 >= cnt) return;

    int tid = threadIdx.x;
    int wave = tid >> 6, lane = tid & 63;

    const unsigned short* ag[2];
#pragma unroll
    for (int i = 0; i < 2; ++i) {
        int slot = wave * 128 + i * 64 + lane;
        int g = slot >> 3, sp = (slot & 7) ^ (g & 7);
        int row = g * 2 + (sp >> 2), c = sp & 3;
        int ar = beg + t0 + row; if (ar > NPAIR - 1) ar = NPAIR - 1;
        ag[i] = act + (size_t)ar * IDIM + c * 8;
    }
    const unsigned short* w2g;
    {
        int slot = wave * 64 + lane;
        int g = slot >> 3, sp = (slot & 7) ^ (g & 7);
        int row = g * 2 + (sp >> 2), c = sp & 3;
        w2g = wb2 + (size_t)e * H * IDIM + (size_t)(h0 + row) * IDIM + c * 8;
    }

    int wr = wave >> 1, wc = wave & 1;
    int lm = lane & 15, lq = lane >> 4;

    f32x4 acc[4][2];
#pragma unroll
    for (int mi = 0; mi < 4; ++mi)
#pragma unroll
        for (int nj = 0; nj < 2; ++nj) acc[mi][nj] = (f32x4){0.f, 0.f, 0.f, 0.f};

    int aoff[4], boff[2];
#pragma unroll
    for (int mi = 0; mi < 4; ++mi) {
        int m = wr * 64 + mi * 16 + lm;
        int g = m >> 1;
        aoff[mi] = g * 64 + (((lq + ((m & 1) << 2)) ^ (g & 7)) << 3);
    }
#pragma unroll
    for (int nj = 0; nj < 2; ++nj) {
        int n = wc * 32 + nj * 16 + lm;
        int g = n >> 1;
        boff[nj] = g * 64 + (((lq + ((n & 1) << 2)) ^ (g & 7)) << 3);
    }

#pragma unroll
    for (int i = 0; i < 2; ++i) async_ld16(ag[i], &As[0][(wave * 128 + i * 64) * 8]);
    async_ld16(w2g, &W2s[0][wave * 512]);

    const int NK = IDIM / 32;
    for (int kk = 0; kk < NK; ++kk) {
        int cur = kk & 1;
        __syncthreads();
        if (kk + 1 < NK) {
            int nxt = cur ^ 1;
            int k1 = (kk + 1) * 32;
#pragma unroll
            for (int i = 0; i < 2; ++i) async_ld16(ag[i] + k1, &As[nxt][(wave * 128 + i * 64) * 8]);
            async_ld16(w2g + k1, &W2s[nxt][wave * 512]);
        }
        bf16x8 af[4], bfr[2];
#pragma unroll
        for (int mi = 0; mi < 4; ++mi) af[mi] = *(const bf16x8*)&As[cur][aoff[mi]];
#pragma unroll
        for (int nj = 0; nj < 2; ++nj) bfr[nj] = *(const bf16x8*)&W2s[cur][boff[nj]];
#pragma unroll
        for (int mi = 0; mi < 4; ++mi)
#pragma unroll
            for (int nj = 0; nj < 2; ++nj)
                acc[mi][nj] = __builtin_amdgcn_mfma_f32_16x16x32_bf16(af[mi], bfr[nj], acc[mi][nj], 0, 0, 0);
    }
#pragma unroll
    for (int mi = 0; mi < 4; ++mi) {
#pragma unroll
        for (int r = 0; r < 4; ++r) {
            int trow = t0 + wr * 64 + mi * 16 + lq * 4 + r;
            if (trow < cnt) {
                unsigned short* orow = outp + (size_t)(beg + trow) * H + h0 + wc * 32 + lm;
#pragma unroll
                for (int nj = 0; nj < 2; ++nj) orow[nj * 16] = f2bf(acc[mi][nj][r]);
            }
        }
    }
}

// ---------------- Combine ----------------
__global__ __launch_bounds__(256) void combine_kernel(
    const unsigned short* __restrict__ outp, const int* __restrict__ inv_pos,
    const float* __restrict__ topk_w, float* __restrict__ out)
{
    int gid = blockIdx.x * 256 + threadIdx.x;
    int t = gid >> 8;
    int c4 = gid & 255;
    float4 a = make_float4(0.f, 0.f, 0.f, 0.f);
#pragma unroll
    for (int k = 0; k < TOPK; ++k) {
        int pos = inv_pos[t * TOPK + k];
        float w = topk_w[t * TOPK + k];
        ushort4 v = ((const ushort4*)(outp + (size_t)pos * H))[c4];
        a.x += w * bf2f(v.x); a.y += w * bf2f(v.y);
        a.z += w * bf2f(v.z); a.w += w * bf2f(v.w);
    }
    *(float4*)(out + (size_t)t * H + c4 * 4) = a;
}

extern "C" void kernel_launch(void* const* d_in, const int* in_sizes, int n_in,
                              void* d_out, int out_size, void* d_ws, size_t ws_size,
                              hipStream_t stream)
{
    const float* x  = (const float*)d_in[0];
    const float* gw = (const float*)d_in[1];
    const float* w1 = (const float*)d_in[2];
    const float* w3 = (const float*)d_in[3];
    const float* w2 = (const float*)d_in[4];
    float* out = (float*)d_out;

    char* ws = (char*)d_ws;
    int*   cursor     = (int*)(ws + 64);
    int*   offsets    = (int*)(ws + 128);
    int*   topk_idx   = (int*)(ws + 1024);
    float* topk_w     = (float*)(ws + 33792);
    int*   pair_token = (int*)(ws + 66560);
    int*   inv_pos    = (int*)(ws + 99328);
    unsigned short* xb  = (unsigned short*)(ws + 262144);    // 4 MB
    unsigned short* wb1 = (unsigned short*)(ws + 8388608);   // 16 MB
    unsigned short* wb3 = (unsigned short*)(ws + 25165824);  // 16 MB
    unsigned short* wb2 = (unsigned short*)(ws + 41943040);  // 16 MB
    unsigned short* act = (unsigned short*)(ws + 58720256);  // 8 MB
    unsigned short* outp = (unsigned short*)(ws + 8388608);  // 16 MB, aliases wb1 (dead after gemm_a)

    hipMemsetAsync(ws, 0, 256, stream);

    router_kernel<<<T / 4, 256, 0, stream>>>(x, gw, topk_idx, topk_w, xb);
    hist_kernel<<<1, 256, 0, stream>>>(topk_idx, offsets);
    scatter_kernel<<<NPAIR / 256, 256, 0, stream>>>(topk_idx, offsets, cursor,
                                                    pair_token, inv_pos);

    cvt3_kernel<<<3 * 2048, 256, 0, stream>>>(w1, w3, w2, wb1, wb3, wb2);

    gemm_a_kernel<<<2048, 256, 0, stream>>>(xb, wb1, wb3, offsets, pair_token, act);
    gemm_b_kernel<<<4096, 256, 0, stream>>>(act, wb2, offsets, outp);
    combine_kernel<<<(T * H / 4) / 256, 256, 0, stream>>>(outp, inv_pos, topk_w, out);
}